// Round 6
// baseline (531.586 us; speedup 1.0000x reference)
//
#include <hip/hip_runtime.h>

#define BB 8
#define HH 256
#define WW 512
#define HW (HH * WW)          // 131072
#define NPIX (BB * HW)        // 1048576

#define TXI 64                // inner tile width
#define TYI 16                // inner tile height
#define HALO 4                // iterations fused per kernel
#define SX (TXI + 2 * HALO)   // 72 staged width
#define SY (TYI + 2 * HALO)   // 24 staged height
#define NST (SX * SY)         // 1728
#define CW (SX - 2)           // 70 computed cols (sx 1..70)
#define CYMAX (SY - 2)        // 22 = last computed staged row
#define RPT 8                 // rows per thread (3 groups: 8+8+6)
#define SYTOP (SY - 1)        // 23, clamp limit

typedef _Float16 half8 __attribute__((ext_vector_type(8)));

// ---------------------------------------------------------------- prep ----
// g_cl = |guidance| fp16 channels-last; d0 = sparse>0 ? sparse : blur.
// XCD-pinned: batch = blockIdx.x & 7 so writes land in the owning XCD's L2.
__global__ __launch_bounds__(256) void prep_kernel(
    const float* __restrict__ guidance,   // [B,8,H,W] NCHW fp32
    const float* __restrict__ blur,
    const float* __restrict__ sparse,
    half8* __restrict__ g_cl,             // [B,H,W,8] fp16
    float* __restrict__ d0)
{
    const int bid = blockIdx.x;
    const int b   = bid & 7;
    const int p   = (bid >> 3) * 256 + threadIdx.x;   // 0..HW-1
    const int idx = b * HW + p;
    const size_t gbase = ((size_t)b * 8) * HW + p;

    half8 h;
#pragma unroll
    for (int c = 0; c < 8; ++c)
        h[c] = (_Float16)fabsf(guidance[gbase + (size_t)c * HW]);
    g_cl[idx] = h;

    const float sp = sparse[idx];
    d0[idx] = (sp > 0.0f) ? sp : blur[idx];
}

// --------------------------------------------------------------- fused ----
// 4 diffusion iterations in LDS. Staged 72x24 (tile + halo 4); outermost
// staged ring frozen at input d; computed region 70x22; inner 64x16 exact
// after 4 iterations. invw computed in-kernel from LDS g (no global array).
__global__ __launch_bounds__(256, 4) void fused_kernel(
    const half8* __restrict__ g_cl,       // [B,H,W,8] fp16
    const float* __restrict__ sparse,     // [B,H,W]
    const float* __restrict__ src,        // [B,H,W] d in
    float* __restrict__ dst)              // [B,H,W] d out
{
    __shared__ _Float16 g_lds[SY][SX][8];   // 27648 B
    __shared__ float    d_lds[SY][SX];      //  6912 B

    const int t    = threadIdx.x;
    const int bid  = blockIdx.x;
    const int b    = bid & 7;               // batch == XCD id (stable)
    const int tile = bid >> 3;              // 0..127
    const int X0   = (tile & 7) * TXI;
    const int Y0   = (tile >> 3) * TYI;

    // ---- stage g and d into LDS (zeros outside image) ----
    for (int idx = t; idx < NST; idx += 256) {
        const int sy = idx / SX;
        const int sx = idx - sy * SX;
        const int gy = Y0 - HALO + sy;
        const int gx = X0 - HALO + sx;
        half8 h;
#pragma unroll
        for (int c = 0; c < 8; ++c) h[c] = (_Float16)0.0f;
        float dv = 0.0f;
        if ((unsigned)gy < HH && (unsigned)gx < WW) {
            const size_t q = ((size_t)b * HH + gy) * WW + gx;
            h  = g_cl[q];
            dv = src[q];
        }
        *(half8*)&g_lds[sy][sx][0] = h;
        d_lds[sy][sx] = dv;
    }
    __syncthreads();

    // ---- per-thread pixel strip: column sxc, rows syB..syB+RPT-1 ----
    const int col = t % CW;                 // 0..69
    const int grp = t / CW;                 // 0..2 compute, 3 mostly idle
    const int sxc = 1 + col;
    const int syB = 1 + grp * RPT;

    unsigned vmask = 0;
#pragma unroll
    for (int k = 0; k < RPT; ++k) {
        const int sy = syB + k;
        const int gy = Y0 - HALO + sy;
        const int gx = X0 - HALO + sxc;
        if (grp < 3 && sy <= CYMAX && (unsigned)gy < HH && (unsigned)gx < WW)
            vmask |= (1u << k);
    }

    // ---- winv from LDS g (rolling row sums of g) ----
    half8 winv[RPT];
    {
        float gs[3][8];
        const int r0 = (syB - 1 < SYTOP) ? (syB - 1) : SYTOP;
        const int r1 = (syB     < SYTOP) ? syB       : SYTOP;
#pragma unroll
        for (int c = 0; c < 8; ++c) { gs[0][c] = 0.0f; gs[1][c] = 0.0f; }
#pragma unroll
        for (int dx = 0; dx < 3; ++dx) {
            const half8 ga = *(const half8*)&g_lds[r0][sxc - 1 + dx][0];
            const half8 gb = *(const half8*)&g_lds[r1][sxc - 1 + dx][0];
#pragma unroll
            for (int c = 0; c < 8; ++c) {
                gs[0][c] += (float)ga[c];
                gs[1][c] += (float)gb[c];
            }
        }
#pragma unroll
        for (int k = 0; k < RPT; ++k) {
            const int rn = syB + 1 + k;
            const int rc = (rn < SYTOP) ? rn : SYTOP;
            float* gn = gs[(2 + k) % 3];
#pragma unroll
            for (int c = 0; c < 8; ++c) gn[c] = 0.0f;
#pragma unroll
            for (int dx = 0; dx < 3; ++dx) {
                const half8 gh = *(const half8*)&g_lds[rc][sxc - 1 + dx][0];
#pragma unroll
                for (int c = 0; c < 8; ++c) gn[c] += (float)gh[c];
            }
            const int ia = k % 3, ib = (k + 1) % 3, ic = (k + 2) % 3;
#pragma unroll
            for (int c = 0; c < 8; ++c) {
                const float ws = gs[ia][c] + gs[ib][c] + gs[ic][c];
                winv[k][c] = (_Float16)(1.0f / ws);
            }
        }
    }

    // ---- sparse values for reinjection ----
    float spv[RPT];
#pragma unroll
    for (int k = 0; k < RPT; ++k) {
        spv[k] = 0.0f;
        if ((vmask >> k) & 1u) {
            const int gy = Y0 - HALO + syB + k;
            const int gx = X0 - HALO + sxc;
            spv[k] = sparse[((size_t)b * HH + gy) * WW + gx];
        }
    }

    // ---- 4 in-LDS iterations ----
    float dnew[RPT];
#pragma unroll
    for (int k = 0; k < RPT; ++k) dnew[k] = 0.0f;

#pragma unroll 1
    for (int it = 0; it < HALO; ++it) {
        float rs[3][8];
        {
            const int r0 = (syB - 1 < SYTOP) ? (syB - 1) : SYTOP;
            const int r1 = (syB     < SYTOP) ? syB       : SYTOP;
#pragma unroll
            for (int c = 0; c < 8; ++c) { rs[0][c] = 0.0f; rs[1][c] = 0.0f; }
#pragma unroll
            for (int dx = 0; dx < 3; ++dx) {
                const half8 ga = *(const half8*)&g_lds[r0][sxc - 1 + dx][0];
                const float da = d_lds[r0][sxc - 1 + dx];
                const half8 gb = *(const half8*)&g_lds[r1][sxc - 1 + dx][0];
                const float db = d_lds[r1][sxc - 1 + dx];
#pragma unroll
                for (int c = 0; c < 8; ++c) {
                    rs[0][c] = fmaf((float)ga[c], da, rs[0][c]);
                    rs[1][c] = fmaf((float)gb[c], db, rs[1][c]);
                }
            }
        }
#pragma unroll
        for (int k = 0; k < RPT; ++k) {
            const int rn = syB + 1 + k;
            const int rc = (rn < SYTOP) ? rn : SYTOP;
            float* rsn = rs[(2 + k) % 3];
#pragma unroll
            for (int c = 0; c < 8; ++c) rsn[c] = 0.0f;
#pragma unroll
            for (int dx = 0; dx < 3; ++dx) {
                const half8 gh = *(const half8*)&g_lds[rc][sxc - 1 + dx][0];
                const float dv = d_lds[rc][sxc - 1 + dx];
#pragma unroll
                for (int c = 0; c < 8; ++c)
                    rsn[c] = fmaf((float)gh[c], dv, rsn[c]);
            }
            const int ia = k % 3, ib = (k + 1) % 3, ic = (k + 2) % 3;
            float m = 0.0f;                       // candidates are >= 0
            const half8 w = winv[k];
#pragma unroll
            for (int c = 0; c < 8; ++c) {
                const float s = rs[ia][c] + rs[ib][c] + rs[ic][c];
                m = fmaxf(m, s * (float)w[c]);
            }
            dnew[k] = (spv[k] > 0.0f) ? spv[k] : m;
        }
        __syncthreads();                          // reads done
#pragma unroll
        for (int k = 0; k < RPT; ++k)
            if ((vmask >> k) & 1u) d_lds[syB + k][sxc] = dnew[k];
        __syncthreads();                          // writes visible
    }

    // ---- write inner 64x16 tile ----
#pragma unroll
    for (int k = 0; k < RPT; ++k) {
        const int sy = syB + k;
        if (((vmask >> k) & 1u) && sxc >= HALO && sxc < HALO + TXI &&
            sy >= HALO && sy < HALO + TYI) {
            const int gy = Y0 - HALO + sy;
            const int gx = X0 - HALO + sxc;
            dst[((size_t)b * HH + gy) * WW + gx] = dnew[k];
        }
    }
}

// -------------------------------------------------------------- launch ----
extern "C" void kernel_launch(void* const* d_in, const int* in_sizes, int n_in,
                              void* d_out, int out_size, void* d_ws, size_t ws_size,
                              hipStream_t stream) {
    const float* guidance = (const float*)d_in[0];
    const float* blur     = (const float*)d_in[1];
    const float* sparse   = (const float*)d_in[2];
    float* out = (float*)d_out;

    half8* g_cl = (half8*)d_ws;                           // 16.78 MB
    float* buf0 = (float*)(g_cl + (size_t)NPIX);          // 4 MB
    float* buf1 = buf0 + (size_t)NPIX;                    // 4 MB

    prep_kernel<<<NPIX / 256, 256, 0, stream>>>(guidance, blur, sparse, g_cl, buf0);

    const int nblk = BB * (WW / TXI) * (HH / TYI);        // 8*8*16 = 1024
    fused_kernel<<<nblk, 256, 0, stream>>>(g_cl, sparse, buf0, buf1);
    fused_kernel<<<nblk, 256, 0, stream>>>(g_cl, sparse, buf1, buf0);
    fused_kernel<<<nblk, 256, 0, stream>>>(g_cl, sparse, buf0, buf1);
    fused_kernel<<<nblk, 256, 0, stream>>>(g_cl, sparse, buf1, out);
}

// Round 7
// 247.191 us; speedup vs baseline: 2.1505x; 2.1505x over previous
//
#include <hip/hip_runtime.h>

#define BB 8
#define HH 256
#define WW 512
#define HW (HH * WW)          // 131072
#define NPIX (BB * HW)        // 1048576

#define TXI 64                // inner tile width
#define TYI 16                // inner tile height
#define HALO 4                // iterations fused per kernel
#define SX (TXI + 2 * HALO)   // 72 staged width
#define SY (TYI + 2 * HALO)   // 24 staged height
#define NST (SX * SY)         // 1728
#define CW (SX - 2)           // 70 computed cols (sx 1..70)
#define CYMAX (SY - 2)        // 22 = last computed staged row
#define RPT 8                 // rows per thread (3 groups: 8+8+6)
#define SYTOP (SY - 1)        // 23, clamp limit

typedef _Float16 half8 __attribute__((ext_vector_type(8)));

// ---------------------------------------------------------------- prep ----
// g_cl = |guidance| fp16 channels-last; d0 = sparse>0 ? sparse : blur.
// XCD-pinned: batch = blockIdx.x & 7 so writes land in the owning XCD's L2.
__global__ __launch_bounds__(256) void prep_kernel(
    const float* __restrict__ guidance,   // [B,8,H,W] NCHW fp32
    const float* __restrict__ blur,
    const float* __restrict__ sparse,
    half8* __restrict__ g_cl,             // [B,H,W,8] fp16
    float* __restrict__ d0)
{
    const int bid = blockIdx.x;
    const int b   = bid & 7;
    const int p   = (bid >> 3) * 256 + threadIdx.x;   // 0..HW-1
    const int idx = b * HW + p;
    const size_t gbase = ((size_t)b * 8) * HW + p;

    half8 h;
#pragma unroll
    for (int c = 0; c < 8; ++c)
        h[c] = (_Float16)fabsf(guidance[gbase + (size_t)c * HW]);
    g_cl[idx] = h;

    const float sp = sparse[idx];
    d0[idx] = (sp > 0.0f) ? sp : blur[idx];
}

// --------------------------------------------------------------- fused ----
// 4 diffusion iterations in LDS. Staged 72x24 (tile + halo 4); outermost
// staged ring frozen at input d; computed region 70x22; inner 64x16 exact
// after 4 iterations. invw computed in-kernel from LDS g (no global array).
// NOTE: no min-waves in launch_bounds — round 6 showed (256,4) caps VGPR at
// 64 and spills ~350 MB/dispatch to scratch. At the natural 128 VGPR we get
// 4 blocks/CU anyway (LDS 34.8 KB x 4 = 139 KB <= 160 KB).
__global__ __launch_bounds__(256) void fused_kernel(
    const half8* __restrict__ g_cl,       // [B,H,W,8] fp16
    const float* __restrict__ sparse,     // [B,H,W]
    const float* __restrict__ src,        // [B,H,W] d in
    float* __restrict__ dst)              // [B,H,W] d out
{
    __shared__ _Float16 g_lds[SY][SX][8];   // 27648 B
    __shared__ float    d_lds[SY][SX];      //  6912 B

    const int t    = threadIdx.x;
    const int bid  = blockIdx.x;
    const int b    = bid & 7;               // batch == XCD id (stable)
    const int tile = bid >> 3;              // 0..127
    const int X0   = (tile & 7) * TXI;
    const int Y0   = (tile >> 3) * TYI;

    // ---- stage g and d into LDS (zeros outside image) ----
    for (int idx = t; idx < NST; idx += 256) {
        const int sy = idx / SX;
        const int sx = idx - sy * SX;
        const int gy = Y0 - HALO + sy;
        const int gx = X0 - HALO + sx;
        half8 h;
#pragma unroll
        for (int c = 0; c < 8; ++c) h[c] = (_Float16)0.0f;
        float dv = 0.0f;
        if ((unsigned)gy < HH && (unsigned)gx < WW) {
            const size_t q = ((size_t)b * HH + gy) * WW + gx;
            h  = g_cl[q];
            dv = src[q];
        }
        *(half8*)&g_lds[sy][sx][0] = h;
        d_lds[sy][sx] = dv;
    }
    __syncthreads();

    // ---- per-thread pixel strip: column sxc, rows syB..syB+RPT-1 ----
    const int col = t % CW;                 // 0..69
    const int grp = t / CW;                 // 0..2 compute, 3 mostly idle
    const int sxc = 1 + col;
    const int syB = 1 + grp * RPT;

    unsigned vmask = 0;
#pragma unroll
    for (int k = 0; k < RPT; ++k) {
        const int sy = syB + k;
        const int gy = Y0 - HALO + sy;
        const int gx = X0 - HALO + sxc;
        if (grp < 3 && sy <= CYMAX && (unsigned)gy < HH && (unsigned)gx < WW)
            vmask |= (1u << k);
    }

    // ---- winv from LDS g (rolling row sums of g) ----
    half8 winv[RPT];
    {
        float gs[3][8];
        const int r0 = (syB - 1 < SYTOP) ? (syB - 1) : SYTOP;
        const int r1 = (syB     < SYTOP) ? syB       : SYTOP;
#pragma unroll
        for (int c = 0; c < 8; ++c) { gs[0][c] = 0.0f; gs[1][c] = 0.0f; }
#pragma unroll
        for (int dx = 0; dx < 3; ++dx) {
            const half8 ga = *(const half8*)&g_lds[r0][sxc - 1 + dx][0];
            const half8 gb = *(const half8*)&g_lds[r1][sxc - 1 + dx][0];
#pragma unroll
            for (int c = 0; c < 8; ++c) {
                gs[0][c] += (float)ga[c];
                gs[1][c] += (float)gb[c];
            }
        }
#pragma unroll
        for (int k = 0; k < RPT; ++k) {
            const int rn = syB + 1 + k;
            const int rc = (rn < SYTOP) ? rn : SYTOP;
            float* gn = gs[(2 + k) % 3];
#pragma unroll
            for (int c = 0; c < 8; ++c) gn[c] = 0.0f;
#pragma unroll
            for (int dx = 0; dx < 3; ++dx) {
                const half8 gh = *(const half8*)&g_lds[rc][sxc - 1 + dx][0];
#pragma unroll
                for (int c = 0; c < 8; ++c) gn[c] += (float)gh[c];
            }
            const int ia = k % 3, ib = (k + 1) % 3, ic = (k + 2) % 3;
#pragma unroll
            for (int c = 0; c < 8; ++c) {
                const float ws = gs[ia][c] + gs[ib][c] + gs[ic][c];
                winv[k][c] = (_Float16)(1.0f / ws);
            }
        }
    }

    // ---- sparse values for reinjection ----
    float spv[RPT];
#pragma unroll
    for (int k = 0; k < RPT; ++k) {
        spv[k] = 0.0f;
        if ((vmask >> k) & 1u) {
            const int gy = Y0 - HALO + syB + k;
            const int gx = X0 - HALO + sxc;
            spv[k] = sparse[((size_t)b * HH + gy) * WW + gx];
        }
    }

    // ---- 4 in-LDS iterations ----
    float dnew[RPT];
#pragma unroll
    for (int k = 0; k < RPT; ++k) dnew[k] = 0.0f;

#pragma unroll 1
    for (int it = 0; it < HALO; ++it) {
        float rs[3][8];
        {
            const int r0 = (syB - 1 < SYTOP) ? (syB - 1) : SYTOP;
            const int r1 = (syB     < SYTOP) ? syB       : SYTOP;
#pragma unroll
            for (int c = 0; c < 8; ++c) { rs[0][c] = 0.0f; rs[1][c] = 0.0f; }
#pragma unroll
            for (int dx = 0; dx < 3; ++dx) {
                const half8 ga = *(const half8*)&g_lds[r0][sxc - 1 + dx][0];
                const float da = d_lds[r0][sxc - 1 + dx];
                const half8 gb = *(const half8*)&g_lds[r1][sxc - 1 + dx][0];
                const float db = d_lds[r1][sxc - 1 + dx];
#pragma unroll
                for (int c = 0; c < 8; ++c) {
                    rs[0][c] = fmaf((float)ga[c], da, rs[0][c]);
                    rs[1][c] = fmaf((float)gb[c], db, rs[1][c]);
                }
            }
        }
#pragma unroll
        for (int k = 0; k < RPT; ++k) {
            const int rn = syB + 1 + k;
            const int rc = (rn < SYTOP) ? rn : SYTOP;
            float* rsn = rs[(2 + k) % 3];
#pragma unroll
            for (int c = 0; c < 8; ++c) rsn[c] = 0.0f;
#pragma unroll
            for (int dx = 0; dx < 3; ++dx) {
                const half8 gh = *(const half8*)&g_lds[rc][sxc - 1 + dx][0];
                const float dv = d_lds[rc][sxc - 1 + dx];
#pragma unroll
                for (int c = 0; c < 8; ++c)
                    rsn[c] = fmaf((float)gh[c], dv, rsn[c]);
            }
            const int ia = k % 3, ib = (k + 1) % 3, ic = (k + 2) % 3;
            float m = 0.0f;                       // candidates are >= 0
            const half8 w = winv[k];
#pragma unroll
            for (int c = 0; c < 8; ++c) {
                const float s = rs[ia][c] + rs[ib][c] + rs[ic][c];
                m = fmaxf(m, s * (float)w[c]);
            }
            dnew[k] = (spv[k] > 0.0f) ? spv[k] : m;
        }
        __syncthreads();                          // reads done
#pragma unroll
        for (int k = 0; k < RPT; ++k)
            if ((vmask >> k) & 1u) d_lds[syB + k][sxc] = dnew[k];
        __syncthreads();                          // writes visible
    }

    // ---- write inner 64x16 tile ----
#pragma unroll
    for (int k = 0; k < RPT; ++k) {
        const int sy = syB + k;
        if (((vmask >> k) & 1u) && sxc >= HALO && sxc < HALO + TXI &&
            sy >= HALO && sy < HALO + TYI) {
            const int gy = Y0 - HALO + sy;
            const int gx = X0 - HALO + sxc;
            dst[((size_t)b * HH + gy) * WW + gx] = dnew[k];
        }
    }
}

// -------------------------------------------------------------- launch ----
extern "C" void kernel_launch(void* const* d_in, const int* in_sizes, int n_in,
                              void* d_out, int out_size, void* d_ws, size_t ws_size,
                              hipStream_t stream) {
    const float* guidance = (const float*)d_in[0];
    const float* blur     = (const float*)d_in[1];
    const float* sparse   = (const float*)d_in[2];
    float* out = (float*)d_out;

    half8* g_cl = (half8*)d_ws;                           // 16.78 MB
    float* buf0 = (float*)(g_cl + (size_t)NPIX);          // 4 MB
    float* buf1 = buf0 + (size_t)NPIX;                    // 4 MB

    prep_kernel<<<NPIX / 256, 256, 0, stream>>>(guidance, blur, sparse, g_cl, buf0);

    const int nblk = BB * (WW / TXI) * (HH / TYI);        // 8*8*16 = 1024
    fused_kernel<<<nblk, 256, 0, stream>>>(g_cl, sparse, buf0, buf1);
    fused_kernel<<<nblk, 256, 0, stream>>>(g_cl, sparse, buf1, buf0);
    fused_kernel<<<nblk, 256, 0, stream>>>(g_cl, sparse, buf0, buf1);
    fused_kernel<<<nblk, 256, 0, stream>>>(g_cl, sparse, buf1, out);
}